// Round 1
// baseline (2732.308 us; speedup 1.0000x reference)
//
#include <hip/hip_runtime.h>

#define N_NODES 100000
#define IN_CH 128
#define OUT_CH 128

// ---------------------------------------------------------------------------
// Kernel 1: h = x @ W   (dense [N,128] @ [128,128] -> [N,128], all f32)
// W (64KB) + 32-row x tile (16KB) staged in LDS; 4x4 register micro-tile.
// ---------------------------------------------------------------------------
__global__ __launch_bounds__(256) void gemm_xw(const float* __restrict__ x,
                                               const float* __restrict__ W,
                                               float* __restrict__ h) {
    __shared__ float Wl[128 * 128];   // 64 KB
    __shared__ float Xl[32 * 128];    // 16 KB
    const int t = threadIdx.x;

    // stage W: 4096 float4 / 256 threads = 16 each (coalesced)
    const float4* W4 = (const float4*)W;
    float4* Wl4 = (float4*)Wl;
#pragma unroll
    for (int i = 0; i < 16; ++i) Wl4[t + 256 * i] = W4[t + 256 * i];

    // stage 32 rows of x: 1024 float4 / 256 threads = 4 each
    const long rbase = (long)blockIdx.x * 32;
    const float4* x4 = (const float4*)(x + rbase * IN_CH);
    float4* Xl4 = (float4*)Xl;
#pragma unroll
    for (int i = 0; i < 4; ++i) Xl4[t + 256 * i] = x4[t + 256 * i];

    __syncthreads();

    const int tx = t & 31;   // 32 col-groups of 4 cols
    const int ty = t >> 5;   // 8 row-groups of 4 rows
    float acc[4][4];
#pragma unroll
    for (int i = 0; i < 4; ++i)
#pragma unroll
        for (int j = 0; j < 4; ++j) acc[i][j] = 0.f;

    for (int k = 0; k < 128; ++k) {
        // threads tx=0..31 read consecutive float4s of row k -> conflict-free
        float4 w = *(const float4*)&Wl[k * 128 + tx * 4];
        float xv[4];
#pragma unroll
        for (int i = 0; i < 4; ++i) xv[i] = Xl[(ty * 4 + i) * 128 + k]; // 2-way max
#pragma unroll
        for (int i = 0; i < 4; ++i) {
            acc[i][0] += xv[i] * w.x;
            acc[i][1] += xv[i] * w.y;
            acc[i][2] += xv[i] * w.z;
            acc[i][3] += xv[i] * w.w;
        }
    }

#pragma unroll
    for (int i = 0; i < 4; ++i) {
        long r = rbase + ty * 4 + i;
        *(float4*)&h[r * OUT_CH + tx * 4] =
            make_float4(acc[i][0], acc[i][1], acc[i][2], acc[i][3]);
    }
}

// ---------------------------------------------------------------------------
// Kernel 2: out[n][c] = bias[c]  (re-initialized every call; harness only
// poisons once, so this makes kernel_launch deterministic)
// ---------------------------------------------------------------------------
__global__ __launch_bounds__(256) void init_bias(float* __restrict__ out,
                                                 const float* __restrict__ bias) {
    int idx = blockIdx.x * 256 + threadIdx.x;      // over N_NODES*32 float4s
    float4 b = ((const float4*)bias)[idx & 31];
    ((float4*)out)[idx] = b;
}

// ---------------------------------------------------------------------------
// Kernel 3: scatter-add  out[row] += w * h[col]  (32 lanes per edge, float4
// gather, 4 scalar f32 atomics per lane)
// ---------------------------------------------------------------------------
__global__ __launch_bounds__(256) void spmm_scatter(const float* __restrict__ h,
                                                    const int* __restrict__ erow,
                                                    const int* __restrict__ ecol,
                                                    const float* __restrict__ ew,
                                                    float* __restrict__ out,
                                                    int n_edges) {
    const int t = threadIdx.x;
    const int lane = t & 31;               // channel group (4 floats each)
    const int e = blockIdx.x * 8 + (t >> 5);
    if (e >= n_edges) return;

    const int r = erow[e];
    const int c = ecol[e];
    const float w = ew[e];

    float4 v = ((const float4*)(h + (long)c * OUT_CH))[lane];
    float* o = out + (long)r * OUT_CH + lane * 4;
    atomicAdd(o + 0, w * v.x);
    atomicAdd(o + 1, w * v.y);
    atomicAdd(o + 2, w * v.z);
    atomicAdd(o + 3, w * v.w);
}

extern "C" void kernel_launch(void* const* d_in, const int* in_sizes, int n_in,
                              void* d_out, int out_size, void* d_ws, size_t ws_size,
                              hipStream_t stream) {
    const float* x    = (const float*)d_in[0];
    const float* W    = (const float*)d_in[1];
    const float* bias = (const float*)d_in[2];
    const int*   erow = (const int*)d_in[3];
    const int*   ecol = (const int*)d_in[4];
    const float* ew   = (const float*)d_in[5];
    float* out = (float*)d_out;
    float* h   = (float*)d_ws;            // 100000*128*4 = 51.2 MB scratch
    const int n_edges = in_sizes[3];

    gemm_xw<<<N_NODES / 32, 256, 0, stream>>>(x, W, h);
    init_bias<<<(N_NODES * 32) / 256, 256, 0, stream>>>(out, bias);
    spmm_scatter<<<(n_edges + 7) / 8, 256, 0, stream>>>(h, erow, ecol, ew, out,
                                                        n_edges);
}

// Round 2
// 373.822 us; speedup vs baseline: 7.3091x; 7.3091x over previous
//
#include <hip/hip_runtime.h>

#define N_NODES 100000
#define N_EDGES_MAX 1600000
#define IN_CH 128
#define OUT_CH 128
#define SCAN_BLOCKS ((N_NODES + 255) / 256)   // 391

// ---------------- workspace layout ----------------
constexpr size_t align_up(size_t x) { return (x + 255) & ~size_t(255); }
constexpr size_t H_OFF     = 0;
constexpr size_t H_SZ      = (size_t)N_NODES * OUT_CH * 4;        // 51.2 MB
constexpr size_t COUNTS_OFF= align_up(H_OFF + H_SZ);
constexpr size_t COUNTS_SZ = (size_t)N_NODES * 4;
constexpr size_t TMP_OFF   = align_up(COUNTS_OFF + COUNTS_SZ);
constexpr size_t BSUM_OFF  = align_up(TMP_OFF + COUNTS_SZ);
constexpr size_t BSUM_SZ   = 4096;
constexpr size_t RS_OFF    = align_up(BSUM_OFF + BSUM_SZ);        // row_start[N+1]
constexpr size_t RS_SZ     = (size_t)(N_NODES + 1) * 4;
constexpr size_t CUR_OFF   = align_up(RS_OFF + RS_SZ);
constexpr size_t SCOL_OFF  = align_up(CUR_OFF + COUNTS_SZ);
constexpr size_t SCOL_SZ   = (size_t)N_EDGES_MAX * 4;
constexpr size_t SW_OFF    = align_up(SCOL_OFF + SCOL_SZ);
constexpr size_t WS_NEED   = SW_OFF + SCOL_SZ;                    // ~65.6 MB

// ---------------------------------------------------------------------------
// Kernel 1: h = x @ W   (dense [N,128] @ [128,128] -> [N,128], all f32)
// ---------------------------------------------------------------------------
__global__ __launch_bounds__(256) void gemm_xw(const float* __restrict__ x,
                                               const float* __restrict__ W,
                                               float* __restrict__ h) {
    __shared__ float Wl[128 * 128];
    __shared__ float Xl[32 * 128];
    const int t = threadIdx.x;

    const float4* W4 = (const float4*)W;
    float4* Wl4 = (float4*)Wl;
#pragma unroll
    for (int i = 0; i < 16; ++i) Wl4[t + 256 * i] = W4[t + 256 * i];

    const long rbase = (long)blockIdx.x * 32;
    const float4* x4 = (const float4*)(x + rbase * IN_CH);
    float4* Xl4 = (float4*)Xl;
#pragma unroll
    for (int i = 0; i < 4; ++i) Xl4[t + 256 * i] = x4[t + 256 * i];

    __syncthreads();

    const int tx = t & 31;
    const int ty = t >> 5;
    float acc[4][4];
#pragma unroll
    for (int i = 0; i < 4; ++i)
#pragma unroll
        for (int j = 0; j < 4; ++j) acc[i][j] = 0.f;

    for (int k = 0; k < 128; ++k) {
        float4 w = *(const float4*)&Wl[k * 128 + tx * 4];
        float xv[4];
#pragma unroll
        for (int i = 0; i < 4; ++i) xv[i] = Xl[(ty * 4 + i) * 128 + k];
#pragma unroll
        for (int i = 0; i < 4; ++i) {
            acc[i][0] += xv[i] * w.x;
            acc[i][1] += xv[i] * w.y;
            acc[i][2] += xv[i] * w.z;
            acc[i][3] += xv[i] * w.w;
        }
    }

#pragma unroll
    for (int i = 0; i < 4; ++i) {
        long r = rbase + ty * 4 + i;
        *(float4*)&h[r * OUT_CH + tx * 4] =
            make_float4(acc[i][0], acc[i][1], acc[i][2], acc[i][3]);
    }
}

// ---------------------------------------------------------------------------
// Counting-sort pipeline (runs every call; all scratch re-initialized here)
// ---------------------------------------------------------------------------
__global__ __launch_bounds__(256) void zero_counts(unsigned* __restrict__ counts) {
    int i = blockIdx.x * 256 + threadIdx.x;
    if (i < N_NODES) counts[i] = 0u;
}

__global__ __launch_bounds__(256) void hist_rows(const int* __restrict__ erow,
                                                 unsigned* __restrict__ counts,
                                                 int n) {
    int e = blockIdx.x * 256 + threadIdx.x;
    if (e < n) atomicAdd(&counts[erow[e]], 1u);
}

__global__ __launch_bounds__(256) void scan_block(const unsigned* __restrict__ counts,
                                                  unsigned* __restrict__ tmp,
                                                  unsigned* __restrict__ bsum) {
    __shared__ unsigned s[256];
    const int b = blockIdx.x, t = threadIdx.x, i = b * 256 + t;
    unsigned v = (i < N_NODES) ? counts[i] : 0u;
    s[t] = v;
    __syncthreads();
    for (int off = 1; off < 256; off <<= 1) {
        unsigned add = (t >= off) ? s[t - off] : 0u;
        __syncthreads();
        s[t] += add;
        __syncthreads();
    }
    if (i < N_NODES) tmp[i] = s[t] - v;           // exclusive
    if (t == 255) bsum[b] = s[255];
}

__global__ __launch_bounds__(512) void scan_top(unsigned* __restrict__ bsum) {
    __shared__ unsigned s[512];
    const int t = threadIdx.x;
    unsigned v = (t < SCAN_BLOCKS) ? bsum[t] : 0u;
    s[t] = v;
    __syncthreads();
    for (int off = 1; off < 512; off <<= 1) {
        unsigned add = (t >= off) ? s[t - off] : 0u;
        __syncthreads();
        s[t] += add;
        __syncthreads();
    }
    if (t < SCAN_BLOCKS) bsum[t] = s[t] - v;      // exclusive
}

__global__ __launch_bounds__(256) void scan_add(const unsigned* __restrict__ tmp,
                                                const unsigned* __restrict__ bsum,
                                                unsigned* __restrict__ row_start,
                                                unsigned* __restrict__ cursor,
                                                int n_edges) {
    const int b = blockIdx.x, t = threadIdx.x, i = b * 256 + t;
    if (i < N_NODES) {
        unsigned v = tmp[i] + bsum[b];
        row_start[i] = v;
        cursor[i] = v;
    }
    if (i == 0) row_start[N_NODES] = (unsigned)n_edges;
}

__global__ __launch_bounds__(256) void scatter_sort(const int* __restrict__ erow,
                                                    const int* __restrict__ ecol,
                                                    const float* __restrict__ ew,
                                                    unsigned* __restrict__ cursor,
                                                    int* __restrict__ scol,
                                                    float* __restrict__ sw,
                                                    int n) {
    int e = blockIdx.x * 256 + threadIdx.x;
    if (e >= n) return;
    int r = erow[e];
    unsigned p = atomicAdd(&cursor[r], 1u);
    scol[p] = ecol[e];
    sw[p] = ew[e];
}

// ---------------------------------------------------------------------------
// Aggregate: out[r] = bias + sum_{e in row r} w_e * h[col_e]   (no atomics)
// 32 lanes own one row's 128 channels (float4/lane); 8 rows per 256-block.
// ---------------------------------------------------------------------------
__global__ __launch_bounds__(256) void aggregate(const float* __restrict__ h,
                                                 const int* __restrict__ scol,
                                                 const float* __restrict__ sw,
                                                 const unsigned* __restrict__ row_start,
                                                 const float* __restrict__ bias,
                                                 float* __restrict__ out) {
    const int t = threadIdx.x, lane = t & 31;
    const int r = blockIdx.x * 8 + (t >> 5);
    if (r >= N_NODES) return;
    const unsigned s = row_start[r], e = row_start[r + 1];
    float4 acc = ((const float4*)bias)[lane];
    const float4* h4 = (const float4*)h;
    for (unsigned i = s; i < e; ++i) {
        int c = scol[i];                 // broadcast within the 32-lane group
        float w = sw[i];
        float4 v = h4[(long)c * 32 + lane];
        acc.x += w * v.x;
        acc.y += w * v.y;
        acc.z += w * v.z;
        acc.w += w * v.w;
    }
    ((float4*)out)[(long)r * 32 + lane] = acc;
}

// ---------------------------------------------------------------------------
// Fallback path (round-1 kernels) if ws_size is too small
// ---------------------------------------------------------------------------
__global__ __launch_bounds__(256) void init_bias(float* __restrict__ out,
                                                 const float* __restrict__ bias) {
    int idx = blockIdx.x * 256 + threadIdx.x;
    float4 b = ((const float4*)bias)[idx & 31];
    ((float4*)out)[idx] = b;
}

__global__ __launch_bounds__(256) void spmm_scatter(const float* __restrict__ h,
                                                    const int* __restrict__ erow,
                                                    const int* __restrict__ ecol,
                                                    const float* __restrict__ ew,
                                                    float* __restrict__ out,
                                                    int n_edges) {
    const int t = threadIdx.x;
    const int lane = t & 31;
    const int e = blockIdx.x * 8 + (t >> 5);
    if (e >= n_edges) return;
    const int r = erow[e];
    const int c = ecol[e];
    const float w = ew[e];
    float4 v = ((const float4*)(h + (long)c * OUT_CH))[lane];
    float* o = out + (long)r * OUT_CH + lane * 4;
    atomicAdd(o + 0, w * v.x);
    atomicAdd(o + 1, w * v.y);
    atomicAdd(o + 2, w * v.z);
    atomicAdd(o + 3, w * v.w);
}

extern "C" void kernel_launch(void* const* d_in, const int* in_sizes, int n_in,
                              void* d_out, int out_size, void* d_ws, size_t ws_size,
                              hipStream_t stream) {
    const float* x    = (const float*)d_in[0];
    const float* W    = (const float*)d_in[1];
    const float* bias = (const float*)d_in[2];
    const int*   erow = (const int*)d_in[3];
    const int*   ecol = (const int*)d_in[4];
    const float* ew   = (const float*)d_in[5];
    float* out = (float*)d_out;
    const int n_edges = in_sizes[3];

    char* ws = (char*)d_ws;
    float*    h        = (float*)(ws + H_OFF);
    unsigned* counts   = (unsigned*)(ws + COUNTS_OFF);
    unsigned* tmp      = (unsigned*)(ws + TMP_OFF);
    unsigned* bsum     = (unsigned*)(ws + BSUM_OFF);
    unsigned* rowstart = (unsigned*)(ws + RS_OFF);
    unsigned* cursor   = (unsigned*)(ws + CUR_OFF);
    int*      scol     = (int*)(ws + SCOL_OFF);
    float*    sw       = (float*)(ws + SW_OFF);

    gemm_xw<<<N_NODES / 32, 256, 0, stream>>>(x, W, h);

    if (ws_size >= WS_NEED && n_edges <= N_EDGES_MAX) {
        const int eblocks = (n_edges + 255) / 256;
        zero_counts<<<SCAN_BLOCKS, 256, 0, stream>>>(counts);
        hist_rows<<<eblocks, 256, 0, stream>>>(erow, counts, n_edges);
        scan_block<<<SCAN_BLOCKS, 256, 0, stream>>>(counts, tmp, bsum);
        scan_top<<<1, 512, 0, stream>>>(bsum);
        scan_add<<<SCAN_BLOCKS, 256, 0, stream>>>(tmp, bsum, rowstart, cursor,
                                                  n_edges);
        scatter_sort<<<eblocks, 256, 0, stream>>>(erow, ecol, ew, cursor, scol,
                                                  sw, n_edges);
        aggregate<<<(N_NODES + 7) / 8, 256, 0, stream>>>(h, scol, sw, rowstart,
                                                         bias, out);
    } else {
        init_bias<<<(N_NODES * 32) / 256, 256, 0, stream>>>(out, bias);
        spmm_scatter<<<(n_edges + 7) / 8, 256, 0, stream>>>(h, erow, ecol, ew,
                                                            out, n_edges);
    }
}

// Round 3
// 291.182 us; speedup vs baseline: 9.3835x; 1.2838x over previous
//
#include <hip/hip_runtime.h>

#define N_NODES 100000
#define N_EDGES_MAX 1600000
#define IN_CH 128
#define OUT_CH 128
#define SCAN_BLOCKS ((N_NODES + 255) / 256)   // 391
#define NB ((N_NODES + 255) / 256)            // 391 buckets of 256 rows
#define EPT 8                                 // edges per thread, phase A

// ---------------- workspace layout ----------------
constexpr size_t align_up(size_t x) { return (x + 255) & ~size_t(255); }
constexpr size_t H_OFF     = 0;
constexpr size_t H_SZ      = (size_t)N_NODES * OUT_CH * 2;        // bf16 h, 25.6 MB
constexpr size_t COUNTS_OFF= align_up(H_OFF + H_SZ);
constexpr size_t COUNTS_SZ = (size_t)N_NODES * 4;
constexpr size_t TMP_OFF   = align_up(COUNTS_OFF + COUNTS_SZ);
constexpr size_t BSUM_OFF  = align_up(TMP_OFF + COUNTS_SZ);
constexpr size_t BSUM_SZ   = 4096;
constexpr size_t RS_OFF    = align_up(BSUM_OFF + BSUM_SZ);        // row_start[N+1]
constexpr size_t RS_SZ     = (size_t)(N_NODES + 1) * 4;
constexpr size_t CUR_OFF   = align_up(RS_OFF + RS_SZ);
constexpr size_t BCUR_OFF  = align_up(CUR_OFF + COUNTS_SZ);
constexpr size_t BCUR_SZ   = (size_t)NB * 4;
constexpr size_t BREC_OFF  = align_up(BCUR_OFF + BCUR_SZ);        // bucket records
constexpr size_t BREC_SZ   = (size_t)N_EDGES_MAX * 8;
constexpr size_t SREC_OFF  = align_up(BREC_OFF + BREC_SZ);        // row-sorted records
constexpr size_t WS_NEED   = SREC_OFF + BREC_SZ;                  // ~53 MB

__device__ __forceinline__ unsigned short f2bf(float f) {
    unsigned u = __float_as_uint(f);
    return (unsigned short)((u + 0x7FFFu + ((u >> 16) & 1u)) >> 16);
}
__device__ __forceinline__ float bf2f(unsigned short b) {
    return __uint_as_float((unsigned)b << 16);
}

// ---------------------------------------------------------------------------
// Kernel 1: h = x @ W  -> bf16  ([N,128] @ [128,128])
// ---------------------------------------------------------------------------
__global__ __launch_bounds__(256) void gemm_xw(const float* __restrict__ x,
                                               const float* __restrict__ W,
                                               unsigned short* __restrict__ h) {
    __shared__ float Wl[128 * 128];
    __shared__ float Xl[32 * 128];
    const int t = threadIdx.x;

    const float4* W4 = (const float4*)W;
    float4* Wl4 = (float4*)Wl;
#pragma unroll
    for (int i = 0; i < 16; ++i) Wl4[t + 256 * i] = W4[t + 256 * i];

    const long rbase = (long)blockIdx.x * 32;
    const float4* x4 = (const float4*)(x + rbase * IN_CH);
    float4* Xl4 = (float4*)Xl;
#pragma unroll
    for (int i = 0; i < 4; ++i) Xl4[t + 256 * i] = x4[t + 256 * i];

    __syncthreads();

    const int tx = t & 31;
    const int ty = t >> 5;
    float acc[4][4];
#pragma unroll
    for (int i = 0; i < 4; ++i)
#pragma unroll
        for (int j = 0; j < 4; ++j) acc[i][j] = 0.f;

    for (int k = 0; k < 128; ++k) {
        float4 w = *(const float4*)&Wl[k * 128 + tx * 4];
        float xv[4];
#pragma unroll
        for (int i = 0; i < 4; ++i) xv[i] = Xl[(ty * 4 + i) * 128 + k];
#pragma unroll
        for (int i = 0; i < 4; ++i) {
            acc[i][0] += xv[i] * w.x;
            acc[i][1] += xv[i] * w.y;
            acc[i][2] += xv[i] * w.z;
            acc[i][3] += xv[i] * w.w;
        }
    }

#pragma unroll
    for (int i = 0; i < 4; ++i) {
        long r = rbase + ty * 4 + i;
        ushort4 o;
        o.x = f2bf(acc[i][0]); o.y = f2bf(acc[i][1]);
        o.z = f2bf(acc[i][2]); o.w = f2bf(acc[i][3]);
        *(ushort4*)&h[r * OUT_CH + tx * 4] = o;
    }
}

// ---------------------------------------------------------------------------
// Histogram + scan (row_start / cursor / bucket cursors)
// ---------------------------------------------------------------------------
__global__ __launch_bounds__(256) void zero_counts(unsigned* __restrict__ counts) {
    int i = blockIdx.x * 256 + threadIdx.x;
    if (i < N_NODES) counts[i] = 0u;
}

__global__ __launch_bounds__(256) void hist_rows(const int* __restrict__ erow,
                                                 unsigned* __restrict__ counts,
                                                 int n) {
    int e = blockIdx.x * 256 + threadIdx.x;
    if (e < n) atomicAdd(&counts[erow[e]], 1u);
}

__global__ __launch_bounds__(256) void scan_block(const unsigned* __restrict__ counts,
                                                  unsigned* __restrict__ tmp,
                                                  unsigned* __restrict__ bsum) {
    __shared__ unsigned s[256];
    const int b = blockIdx.x, t = threadIdx.x, i = b * 256 + t;
    unsigned v = (i < N_NODES) ? counts[i] : 0u;
    s[t] = v;
    __syncthreads();
    for (int off = 1; off < 256; off <<= 1) {
        unsigned add = (t >= off) ? s[t - off] : 0u;
        __syncthreads();
        s[t] += add;
        __syncthreads();
    }
    if (i < N_NODES) tmp[i] = s[t] - v;
    if (t == 255) bsum[b] = s[255];
}

__global__ __launch_bounds__(512) void scan_top(unsigned* __restrict__ bsum) {
    __shared__ unsigned s[512];
    const int t = threadIdx.x;
    unsigned v = (t < SCAN_BLOCKS) ? bsum[t] : 0u;
    s[t] = v;
    __syncthreads();
    for (int off = 1; off < 512; off <<= 1) {
        unsigned add = (t >= off) ? s[t - off] : 0u;
        __syncthreads();
        s[t] += add;
        __syncthreads();
    }
    if (t < SCAN_BLOCKS) bsum[t] = s[t] - v;
}

__global__ __launch_bounds__(256) void scan_add(const unsigned* __restrict__ tmp,
                                                const unsigned* __restrict__ bsum,
                                                unsigned* __restrict__ row_start,
                                                unsigned* __restrict__ cursor,
                                                unsigned* __restrict__ bcursor,
                                                int n_edges) {
    const int b = blockIdx.x, t = threadIdx.x, i = b * 256 + t;
    if (i < N_NODES) {
        unsigned v = tmp[i] + bsum[b];
        row_start[i] = v;
        cursor[i] = v;
        if ((i & 255) == 0) bcursor[i >> 8] = v;   // bucket base = row_start[b<<8]
    }
    if (i == 0) row_start[N_NODES] = (unsigned)n_edges;
}

// ---------------------------------------------------------------------------
// Phase A: scatter edges into 391 buckets (256 rows each), packed 8B records.
// LDS-ranked block-aggregated cursor atomics -> each bucket is a dense
// sequential write stream (L2-friendly).
// record.x = (row&255)<<17 | col   record.y = bits(w)
// ---------------------------------------------------------------------------
__global__ __launch_bounds__(256) void bucket_scatter(const int* __restrict__ erow,
                                                      const int* __restrict__ ecol,
                                                      const float* __restrict__ ew,
                                                      unsigned* __restrict__ bcursor,
                                                      uint2* __restrict__ brec,
                                                      int n) {
    __shared__ unsigned cnt[NB];
    __shared__ unsigned base[NB];
    const int t = threadIdx.x;
    for (int i = t; i < NB; i += 256) cnt[i] = 0u;
    __syncthreads();

    const int e0 = blockIdx.x * (256 * EPT);
    unsigned bk[EPT], rk[EPT], mt[EPT];
    float wv[EPT];
#pragma unroll
    for (int i = 0; i < EPT; ++i) {
        int e = e0 + i * 256 + t;
        if (e < n) {
            int r = erow[e];
            int c = ecol[e];
            wv[i] = ew[e];
            bk[i] = (unsigned)r >> 8;
            mt[i] = ((unsigned)(r & 255) << 17) | (unsigned)c;
            rk[i] = atomicAdd(&cnt[bk[i]], 1u);
        } else {
            bk[i] = 0xFFFFFFFFu;
        }
    }
    __syncthreads();
    for (int i = t; i < NB; i += 256)
        base[i] = cnt[i] ? atomicAdd(&bcursor[i], cnt[i]) : 0u;
    __syncthreads();
#pragma unroll
    for (int i = 0; i < EPT; ++i) {
        if (bk[i] != 0xFFFFFFFFu) {
            unsigned p = base[bk[i]] + rk[i];
            brec[p] = make_uint2(mt[i], __float_as_uint(wv[i]));
        }
    }
}

// ---------------------------------------------------------------------------
// Phase B: one block per bucket; place records at final row-sorted position.
// Destinations lie in the bucket's ~32KB contiguous window -> L2 hits.
// ---------------------------------------------------------------------------
__global__ __launch_bounds__(256) void row_scatter(const uint2* __restrict__ brec,
                                                   const unsigned* __restrict__ row_start,
                                                   unsigned* __restrict__ cursor,
                                                   uint2* __restrict__ srec) {
    const int b = blockIdx.x;
    const unsigned s = row_start[b << 8];
    const int hi = (b + 1) << 8;
    const unsigned e = row_start[hi > N_NODES ? N_NODES : hi];
    for (unsigned i = s + threadIdx.x; i < e; i += 256) {
        uint2 rec = brec[i];
        unsigned row = ((unsigned)b << 8) + (rec.x >> 17);
        unsigned col = rec.x & 0x1FFFFu;
        unsigned p = atomicAdd(&cursor[row], 1u);
        srec[p] = make_uint2(col, rec.y);
    }
}

// ---------------------------------------------------------------------------
// Aggregate: out[r] = bias + sum w_e * h[col_e]  (no atomics, bf16 h)
// 32 lanes own a row (4 ch each); 8 rows per block.
// ---------------------------------------------------------------------------
__global__ __launch_bounds__(256) void aggregate(const unsigned short* __restrict__ h,
                                                 const uint2* __restrict__ srec,
                                                 const unsigned* __restrict__ row_start,
                                                 const float* __restrict__ bias,
                                                 float* __restrict__ out) {
    const int t = threadIdx.x, lane = t & 31;
    const int r = blockIdx.x * 8 + (t >> 5);
    if (r >= N_NODES) return;
    const unsigned s = row_start[r], e = row_start[r + 1];
    float4 acc = ((const float4*)bias)[lane];
    const ushort4* h4 = (const ushort4*)h;
    for (unsigned i = s; i < e; ++i) {
        uint2 rec = srec[i];
        float w = __uint_as_float(rec.y);
        ushort4 hv = h4[(size_t)rec.x * 32 + lane];
        acc.x += w * bf2f(hv.x);
        acc.y += w * bf2f(hv.y);
        acc.z += w * bf2f(hv.z);
        acc.w += w * bf2f(hv.w);
    }
    ((float4*)out)[(size_t)r * 32 + lane] = acc;
}

// ---------------------------------------------------------------------------
// Fallback (atomic) path if ws_size too small
// ---------------------------------------------------------------------------
__global__ __launch_bounds__(256) void init_bias(float* __restrict__ out,
                                                 const float* __restrict__ bias) {
    int idx = blockIdx.x * 256 + threadIdx.x;
    float4 b = ((const float4*)bias)[idx & 31];
    ((float4*)out)[idx] = b;
}

__global__ __launch_bounds__(256) void spmm_scatter(const unsigned short* __restrict__ h,
                                                    const int* __restrict__ erow,
                                                    const int* __restrict__ ecol,
                                                    const float* __restrict__ ew,
                                                    float* __restrict__ out,
                                                    int n_edges) {
    const int t = threadIdx.x;
    const int lane = t & 31;
    const int e = blockIdx.x * 8 + (t >> 5);
    if (e >= n_edges) return;
    const int r = erow[e];
    const int c = ecol[e];
    const float w = ew[e];
    ushort4 hv = ((const ushort4*)(h + (size_t)c * OUT_CH))[lane];
    float* o = out + (size_t)r * OUT_CH + lane * 4;
    atomicAdd(o + 0, w * bf2f(hv.x));
    atomicAdd(o + 1, w * bf2f(hv.y));
    atomicAdd(o + 2, w * bf2f(hv.z));
    atomicAdd(o + 3, w * bf2f(hv.w));
}

extern "C" void kernel_launch(void* const* d_in, const int* in_sizes, int n_in,
                              void* d_out, int out_size, void* d_ws, size_t ws_size,
                              hipStream_t stream) {
    const float* x    = (const float*)d_in[0];
    const float* W    = (const float*)d_in[1];
    const float* bias = (const float*)d_in[2];
    const int*   erow = (const int*)d_in[3];
    const int*   ecol = (const int*)d_in[4];
    const float* ew   = (const float*)d_in[5];
    float* out = (float*)d_out;
    const int n_edges = in_sizes[3];

    char* ws = (char*)d_ws;
    unsigned short* h  = (unsigned short*)(ws + H_OFF);
    unsigned* counts   = (unsigned*)(ws + COUNTS_OFF);
    unsigned* tmp      = (unsigned*)(ws + TMP_OFF);
    unsigned* bsum     = (unsigned*)(ws + BSUM_OFF);
    unsigned* rowstart = (unsigned*)(ws + RS_OFF);
    unsigned* cursor   = (unsigned*)(ws + CUR_OFF);
    unsigned* bcursor  = (unsigned*)(ws + BCUR_OFF);
    uint2*    brec     = (uint2*)(ws + BREC_OFF);
    uint2*    srec     = (uint2*)(ws + SREC_OFF);

    gemm_xw<<<N_NODES / 32, 256, 0, stream>>>(x, W, h);

    if (ws_size >= WS_NEED && n_edges <= N_EDGES_MAX) {
        const int eblocks = (n_edges + 255) / 256;
        const int ablocks = (n_edges + 256 * EPT - 1) / (256 * EPT);
        zero_counts<<<SCAN_BLOCKS, 256, 0, stream>>>(counts);
        hist_rows<<<eblocks, 256, 0, stream>>>(erow, counts, n_edges);
        scan_block<<<SCAN_BLOCKS, 256, 0, stream>>>(counts, tmp, bsum);
        scan_top<<<1, 512, 0, stream>>>(bsum);
        scan_add<<<SCAN_BLOCKS, 256, 0, stream>>>(tmp, bsum, rowstart, cursor,
                                                  bcursor, n_edges);
        bucket_scatter<<<ablocks, 256, 0, stream>>>(erow, ecol, ew, bcursor,
                                                    brec, n_edges);
        row_scatter<<<NB, 256, 0, stream>>>(brec, rowstart, cursor, srec);
        aggregate<<<(N_NODES + 7) / 8, 256, 0, stream>>>(h, srec, rowstart,
                                                         bias, out);
    } else {
        init_bias<<<(N_NODES * 32) / 256, 256, 0, stream>>>(out, bias);
        spmm_scatter<<<(n_edges + 7) / 8, 256, 0, stream>>>(h, erow, ecol, ew,
                                                            out, n_edges);
    }
}

// Round 5
// 256.020 us; speedup vs baseline: 10.6722x; 1.1373x over previous
//
#include <hip/hip_runtime.h>

#define N_NODES 100000
#define N_EDGES_MAX 1600000
#define IN_CH 128
#define OUT_CH 128
#define SCAN_BLOCKS ((N_NODES + 255) / 256)   // 391
#define NB ((N_NODES + 255) / 256)            // 391 buckets of 256 rows
#define EPT 8                                 // edges per thread, phase A

// ---------------- workspace layout ----------------
constexpr size_t align_up(size_t x) { return (x + 255) & ~size_t(255); }
constexpr size_t H_OFF     = 0;
constexpr size_t H_SZ      = (size_t)N_NODES * OUT_CH * 2;        // bf16 h, 25.6 MB
constexpr size_t COUNTS_OFF= align_up(H_OFF + H_SZ);
constexpr size_t COUNTS_SZ = (size_t)N_NODES * 4;
constexpr size_t TMP_OFF   = align_up(COUNTS_OFF + COUNTS_SZ);
constexpr size_t BSUM_OFF  = align_up(TMP_OFF + COUNTS_SZ);
constexpr size_t BSUM_SZ   = 4096;
constexpr size_t RS_OFF    = align_up(BSUM_OFF + BSUM_SZ);        // row_start[N+1]
constexpr size_t RS_SZ     = (size_t)(N_NODES + 1) * 4;
constexpr size_t CUR_OFF   = align_up(RS_OFF + RS_SZ);
constexpr size_t BCUR_OFF  = align_up(CUR_OFF + COUNTS_SZ);
constexpr size_t BCUR_SZ   = (size_t)NB * 4;
constexpr size_t BREC_OFF  = align_up(BCUR_OFF + BCUR_SZ);        // bucket records
constexpr size_t BREC_SZ   = (size_t)N_EDGES_MAX * 8;
constexpr size_t SREC_OFF  = align_up(BREC_OFF + BREC_SZ);        // row-sorted records
constexpr size_t WS_NEED   = SREC_OFF + BREC_SZ;                  // ~53 MB

__device__ __forceinline__ unsigned short f2bf(float f) {
    unsigned u = __float_as_uint(f);
    return (unsigned short)((u + 0x7FFFu + ((u >> 16) & 1u)) >> 16);
}
__device__ __forceinline__ float bf2f(unsigned short b) {
    return __uint_as_float((unsigned)b << 16);
}
// packed-word bf16 -> f32: low half = shift, high half = mask (free VALU op)
__device__ __forceinline__ float bflo(unsigned u) { return __uint_as_float(u << 16); }
__device__ __forceinline__ float bfhi(unsigned u) { return __uint_as_float(u & 0xFFFF0000u); }

__device__ __forceinline__ void accum8(float4& a0, float4& a1, const uint4 hv,
                                       const float wt) {
    a0.x += wt * bflo(hv.x); a0.y += wt * bfhi(hv.x);
    a0.z += wt * bflo(hv.y); a0.w += wt * bfhi(hv.y);
    a1.x += wt * bflo(hv.z); a1.y += wt * bfhi(hv.z);
    a1.z += wt * bflo(hv.w); a1.w += wt * bfhi(hv.w);
}

// ---------------------------------------------------------------------------
// Kernel 1: h = x @ W  -> bf16  ([N,128] @ [128,128])
// ---------------------------------------------------------------------------
__global__ __launch_bounds__(256) void gemm_xw(const float* __restrict__ x,
                                               const float* __restrict__ W,
                                               unsigned short* __restrict__ h) {
    __shared__ float Wl[128 * 128];
    __shared__ float Xl[32 * 128];
    const int t = threadIdx.x;

    const float4* W4 = (const float4*)W;
    float4* Wl4 = (float4*)Wl;
#pragma unroll
    for (int i = 0; i < 16; ++i) Wl4[t + 256 * i] = W4[t + 256 * i];

    const long rbase = (long)blockIdx.x * 32;
    const float4* x4 = (const float4*)(x + rbase * IN_CH);
    float4* Xl4 = (float4*)Xl;
#pragma unroll
    for (int i = 0; i < 4; ++i) Xl4[t + 256 * i] = x4[t + 256 * i];

    __syncthreads();

    const int tx = t & 31;
    const int ty = t >> 5;
    float acc[4][4];
#pragma unroll
    for (int i = 0; i < 4; ++i)
#pragma unroll
        for (int j = 0; j < 4; ++j) acc[i][j] = 0.f;

    for (int k = 0; k < 128; ++k) {
        float4 w = *(const float4*)&Wl[k * 128 + tx * 4];
        float xv[4];
#pragma unroll
        for (int i = 0; i < 4; ++i) xv[i] = Xl[(ty * 4 + i) * 128 + k];
#pragma unroll
        for (int i = 0; i < 4; ++i) {
            acc[i][0] += xv[i] * w.x;
            acc[i][1] += xv[i] * w.y;
            acc[i][2] += xv[i] * w.z;
            acc[i][3] += xv[i] * w.w;
        }
    }

#pragma unroll
    for (int i = 0; i < 4; ++i) {
        long r = rbase + ty * 4 + i;
        ushort4 o;
        o.x = f2bf(acc[i][0]); o.y = f2bf(acc[i][1]);
        o.z = f2bf(acc[i][2]); o.w = f2bf(acc[i][3]);
        *(ushort4*)&h[r * OUT_CH + tx * 4] = o;
    }
}

// ---------------------------------------------------------------------------
// Histogram + scan (row_start / cursor / bucket cursors)
// ---------------------------------------------------------------------------
__global__ __launch_bounds__(256) void zero_counts(unsigned* __restrict__ counts) {
    int i = blockIdx.x * 256 + threadIdx.x;
    if (i < N_NODES) counts[i] = 0u;
}

__global__ __launch_bounds__(256) void hist_rows(const int* __restrict__ erow,
                                                 unsigned* __restrict__ counts,
                                                 int n) {
    int e = blockIdx.x * 256 + threadIdx.x;
    if (e < n) atomicAdd(&counts[erow[e]], 1u);
}

__global__ __launch_bounds__(256) void scan_block(const unsigned* __restrict__ counts,
                                                  unsigned* __restrict__ tmp,
                                                  unsigned* __restrict__ bsum) {
    __shared__ unsigned s[256];
    const int b = blockIdx.x, t = threadIdx.x, i = b * 256 + t;
    unsigned v = (i < N_NODES) ? counts[i] : 0u;
    s[t] = v;
    __syncthreads();
    for (int off = 1; off < 256; off <<= 1) {
        unsigned add = (t >= off) ? s[t - off] : 0u;
        __syncthreads();
        s[t] += add;
        __syncthreads();
    }
    if (i < N_NODES) tmp[i] = s[t] - v;
    if (t == 255) bsum[b] = s[255];
}

__global__ __launch_bounds__(512) void scan_top(unsigned* __restrict__ bsum) {
    __shared__ unsigned s[512];
    const int t = threadIdx.x;
    unsigned v = (t < SCAN_BLOCKS) ? bsum[t] : 0u;
    s[t] = v;
    __syncthreads();
    for (int off = 1; off < 512; off <<= 1) {
        unsigned add = (t >= off) ? s[t - off] : 0u;
        __syncthreads();
        s[t] += add;
        __syncthreads();
    }
    if (t < SCAN_BLOCKS) bsum[t] = s[t] - v;
}

__global__ __launch_bounds__(256) void scan_add(const unsigned* __restrict__ tmp,
                                                const unsigned* __restrict__ bsum,
                                                unsigned* __restrict__ row_start,
                                                unsigned* __restrict__ cursor,
                                                unsigned* __restrict__ bcursor,
                                                int n_edges) {
    const int b = blockIdx.x, t = threadIdx.x, i = b * 256 + t;
    if (i < N_NODES) {
        unsigned v = tmp[i] + bsum[b];
        row_start[i] = v;
        cursor[i] = v;
        if ((i & 255) == 0) bcursor[i >> 8] = v;   // bucket base = row_start[b<<8]
    }
    if (i == 0) row_start[N_NODES] = (unsigned)n_edges;
}

// ---------------------------------------------------------------------------
// Phase A: scatter edges into 391 buckets (256 rows each), packed 8B records.
// record.x = (row&255)<<17 | col   record.y = bits(w)
// ---------------------------------------------------------------------------
__global__ __launch_bounds__(256) void bucket_scatter(const int* __restrict__ erow,
                                                      const int* __restrict__ ecol,
                                                      const float* __restrict__ ew,
                                                      unsigned* __restrict__ bcursor,
                                                      uint2* __restrict__ brec,
                                                      int n) {
    __shared__ unsigned cnt[NB];
    __shared__ unsigned base[NB];
    const int t = threadIdx.x;
    for (int i = t; i < NB; i += 256) cnt[i] = 0u;
    __syncthreads();

    const int e0 = blockIdx.x * (256 * EPT);
    unsigned bk[EPT], rk[EPT], mt[EPT];
    float wv[EPT];
#pragma unroll
    for (int i = 0; i < EPT; ++i) {
        int e = e0 + i * 256 + t;
        if (e < n) {
            int r = erow[e];
            int c = ecol[e];
            wv[i] = ew[e];
            bk[i] = (unsigned)r >> 8;
            mt[i] = ((unsigned)(r & 255) << 17) | (unsigned)c;
            rk[i] = atomicAdd(&cnt[bk[i]], 1u);
        } else {
            bk[i] = 0xFFFFFFFFu;
        }
    }
    __syncthreads();
    for (int i = t; i < NB; i += 256)
        base[i] = cnt[i] ? atomicAdd(&bcursor[i], cnt[i]) : 0u;
    __syncthreads();
#pragma unroll
    for (int i = 0; i < EPT; ++i) {
        if (bk[i] != 0xFFFFFFFFu) {
            unsigned p = base[bk[i]] + rk[i];
            brec[p] = make_uint2(mt[i], __float_as_uint(wv[i]));
        }
    }
}

// ---------------------------------------------------------------------------
// Phase B: one block per bucket; place records at final row-sorted position.
// ---------------------------------------------------------------------------
__global__ __launch_bounds__(256) void row_scatter(const uint2* __restrict__ brec,
                                                   const unsigned* __restrict__ row_start,
                                                   unsigned* __restrict__ cursor,
                                                   uint2* __restrict__ srec) {
    const int b = blockIdx.x;
    const unsigned s = row_start[b << 8];
    const int hi = (b + 1) << 8;
    const unsigned e = row_start[hi > N_NODES ? N_NODES : hi];
    for (unsigned i = s + threadIdx.x; i < e; i += 256) {
        uint2 rec = brec[i];
        unsigned row = ((unsigned)b << 8) + (rec.x >> 17);
        unsigned col = rec.x & 0x1FFFFu;
        unsigned p = atomicAdd(&cursor[row], 1u);
        srec[p] = make_uint2(col, rec.y);
    }
}

// ---------------------------------------------------------------------------
// Aggregate: out[r] = bias + sum w_e * h[col_e]   (no atomics, bf16 h)
// 16 lanes own a row (8 ch = 16B/lane); 4 independent row-chains per wave;
// 4x unrolled edge loop -> up to 16 outstanding gathers per wave.
// ---------------------------------------------------------------------------
__global__ __launch_bounds__(256) void aggregate(const unsigned short* __restrict__ h,
                                                 const uint2* __restrict__ srec,
                                                 const unsigned* __restrict__ row_start,
                                                 const float* __restrict__ bias,
                                                 float* __restrict__ out) {
    const int t = threadIdx.x, lane = t & 15;
    const int r = blockIdx.x * 16 + (t >> 4);
    if (r >= N_NODES) return;
    const unsigned s = row_start[r], e = row_start[r + 1];

    const float4* b4 = (const float4*)bias;
    float4 a0 = b4[lane * 2];
    float4 a1 = b4[lane * 2 + 1];

    const uint4* h16 = (const uint4*)h;        // 16B = 8 bf16; row stride 16

    unsigned i = s;
    for (; i + 4 <= e; i += 4) {
        uint2 r0 = srec[i];
        uint2 r1 = srec[i + 1];
        uint2 r2 = srec[i + 2];
        uint2 r3 = srec[i + 3];
        uint4 v0 = h16[(size_t)r0.x * 16 + lane];
        uint4 v1 = h16[(size_t)r1.x * 16 + lane];
        uint4 v2 = h16[(size_t)r2.x * 16 + lane];
        uint4 v3 = h16[(size_t)r3.x * 16 + lane];
        accum8(a0, a1, v0, __uint_as_float(r0.y));
        accum8(a0, a1, v1, __uint_as_float(r1.y));
        accum8(a0, a1, v2, __uint_as_float(r2.y));
        accum8(a0, a1, v3, __uint_as_float(r3.y));
    }
    for (; i < e; ++i) {
        uint2 rc = srec[i];
        uint4 v = h16[(size_t)rc.x * 16 + lane];
        accum8(a0, a1, v, __uint_as_float(rc.y));
    }

    float4* o = (float4*)(out + (size_t)r * OUT_CH + lane * 8);
    o[0] = a0;
    o[1] = a1;
}

// ---------------------------------------------------------------------------
// Fallback (atomic) path if ws_size too small
// ---------------------------------------------------------------------------
__global__ __launch_bounds__(256) void init_bias(float* __restrict__ out,
                                                 const float* __restrict__ bias) {
    int idx = blockIdx.x * 256 + threadIdx.x;
    float4 b = ((const float4*)bias)[idx & 31];
    ((float4*)out)[idx] = b;
}

__global__ __launch_bounds__(256) void spmm_scatter(const unsigned short* __restrict__ h,
                                                    const int* __restrict__ erow,
                                                    const int* __restrict__ ecol,
                                                    const float* __restrict__ ew,
                                                    float* __restrict__ out,
                                                    int n_edges) {
    const int t = threadIdx.x;
    const int lane = t & 31;
    const int e = blockIdx.x * 8 + (t >> 5);
    if (e >= n_edges) return;
    const int r = erow[e];
    const int c = ecol[e];
    const float w = ew[e];
    ushort4 hv = ((const ushort4*)(h + (size_t)c * OUT_CH))[lane];
    float* o = out + (size_t)r * OUT_CH + lane * 4;
    atomicAdd(o + 0, w * bf2f(hv.x));
    atomicAdd(o + 1, w * bf2f(hv.y));
    atomicAdd(o + 2, w * bf2f(hv.z));
    atomicAdd(o + 3, w * bf2f(hv.w));
}

extern "C" void kernel_launch(void* const* d_in, const int* in_sizes, int n_in,
                              void* d_out, int out_size, void* d_ws, size_t ws_size,
                              hipStream_t stream) {
    const float* x    = (const float*)d_in[0];
    const float* W    = (const float*)d_in[1];
    const float* bias = (const float*)d_in[2];
    const int*   erow = (const int*)d_in[3];
    const int*   ecol = (const int*)d_in[4];
    const float* ew   = (const float*)d_in[5];
    float* out = (float*)d_out;
    const int n_edges = in_sizes[3];

    char* ws = (char*)d_ws;
    unsigned short* h  = (unsigned short*)(ws + H_OFF);
    unsigned* counts   = (unsigned*)(ws + COUNTS_OFF);
    unsigned* tmp      = (unsigned*)(ws + TMP_OFF);
    unsigned* bsum     = (unsigned*)(ws + BSUM_OFF);
    unsigned* rowstart = (unsigned*)(ws + RS_OFF);
    unsigned* cursor   = (unsigned*)(ws + CUR_OFF);
    unsigned* bcursor  = (unsigned*)(ws + BCUR_OFF);
    uint2*    brec     = (uint2*)(ws + BREC_OFF);
    uint2*    srec     = (uint2*)(ws + SREC_OFF);

    gemm_xw<<<N_NODES / 32, 256, 0, stream>>>(x, W, h);

    if (ws_size >= WS_NEED && n_edges <= N_EDGES_MAX) {
        const int eblocks = (n_edges + 255) / 256;
        const int ablocks = (n_edges + 256 * EPT - 1) / (256 * EPT);
        zero_counts<<<SCAN_BLOCKS, 256, 0, stream>>>(counts);
        hist_rows<<<eblocks, 256, 0, stream>>>(erow, counts, n_edges);
        scan_block<<<SCAN_BLOCKS, 256, 0, stream>>>(counts, tmp, bsum);
        scan_top<<<1, 512, 0, stream>>>(bsum);
        scan_add<<<SCAN_BLOCKS, 256, 0, stream>>>(tmp, bsum, rowstart, cursor,
                                                  bcursor, n_edges);
        bucket_scatter<<<ablocks, 256, 0, stream>>>(erow, ecol, ew, bcursor,
                                                    brec, n_edges);
        row_scatter<<<NB, 256, 0, stream>>>(brec, rowstart, cursor, srec);
        aggregate<<<(N_NODES + 15) / 16, 256, 0, stream>>>(h, srec, rowstart,
                                                           bias, out);
    } else {
        init_bias<<<(N_NODES * 32) / 256, 256, 0, stream>>>(out, bias);
        spmm_scatter<<<(n_edges + 7) / 8, 256, 0, stream>>>(h, erow, ecol, ew,
                                                            out, n_edges);
    }
}

// Round 6
// 164.571 us; speedup vs baseline: 16.6026x; 1.5557x over previous
//
#include <hip/hip_runtime.h>

#define N_NODES 100000
#define N_EDGES_MAX 1600000
#define IN_CH 128
#define OUT_CH 128
#define NB 391                 // buckets of 256 rows: ceil(100000/256)
#define BLK_E 2048             // edges per block in hist/scatter
#define NBLK_MAX ((N_EDGES_MAX + BLK_E - 1) / BLK_E)   // 782
#define NBLK_P 800             // padded block count in blkcnt matrix
#define CAP_LDS 5120           // LDS staging capacity per bucket (records)

// ---------------- workspace layout ----------------
constexpr size_t align_up(size_t x) { return (x + 255) & ~size_t(255); }
constexpr size_t H_OFF     = 0;
constexpr size_t H_SZ      = (size_t)N_NODES * OUT_CH * 2;        // bf16 h, 25.6 MB
constexpr size_t BREC_OFF  = align_up(H_OFF + H_SZ);
constexpr size_t BREC_SZ   = (size_t)N_EDGES_MAX * 8;             // 12.8 MB
constexpr size_t SREC_OFF  = align_up(BREC_OFF + BREC_SZ);        // 12.8 MB
constexpr size_t BLK_OFF   = align_up(SREC_OFF + BREC_SZ);        // blkcnt matrix
constexpr size_t BLK_SZ    = (size_t)NB * NBLK_P * 4;             // 1.25 MB
constexpr size_t BTOT_OFF  = align_up(BLK_OFF + BLK_SZ);
constexpr size_t BTOT_SZ   = (size_t)NB * 4;
constexpr size_t BBASE_OFF = align_up(BTOT_OFF + BTOT_SZ);
constexpr size_t BBASE_SZ  = (size_t)(NB + 1) * 4;
constexpr size_t RS_OFF    = align_up(BBASE_OFF + BBASE_SZ);      // row_start[N+1]
constexpr size_t RS_SZ     = (size_t)(N_NODES + 1) * 4;
constexpr size_t WS_NEED   = RS_OFF + RS_SZ;                      // ~52.9 MB

__device__ __forceinline__ unsigned short f2bf(float f) {
    unsigned u = __float_as_uint(f);
    return (unsigned short)((u + 0x7FFFu + ((u >> 16) & 1u)) >> 16);
}
__device__ __forceinline__ float bf2f(unsigned short b) {
    return __uint_as_float((unsigned)b << 16);
}
__device__ __forceinline__ float bflo(unsigned u) { return __uint_as_float(u << 16); }
__device__ __forceinline__ float bfhi(unsigned u) { return __uint_as_float(u & 0xFFFF0000u); }

__device__ __forceinline__ void accum8(float4& a0, float4& a1, const uint4 hv,
                                       const float wt) {
    a0.x += wt * bflo(hv.x); a0.y += wt * bfhi(hv.x);
    a0.z += wt * bflo(hv.y); a0.w += wt * bfhi(hv.y);
    a1.x += wt * bflo(hv.z); a1.y += wt * bfhi(hv.z);
    a1.z += wt * bflo(hv.w); a1.w += wt * bfhi(hv.w);
}

// ---------------------------------------------------------------------------
// K1: h = x @ W  -> bf16  ([N,128] @ [128,128])
// ---------------------------------------------------------------------------
__global__ __launch_bounds__(256) void gemm_xw(const float* __restrict__ x,
                                               const float* __restrict__ W,
                                               unsigned short* __restrict__ h) {
    __shared__ float Wl[128 * 128];
    __shared__ float Xl[32 * 128];
    const int t = threadIdx.x;

    const float4* W4 = (const float4*)W;
    float4* Wl4 = (float4*)Wl;
#pragma unroll
    for (int i = 0; i < 16; ++i) Wl4[t + 256 * i] = W4[t + 256 * i];

    const long rbase = (long)blockIdx.x * 32;
    const float4* x4 = (const float4*)(x + rbase * IN_CH);
    float4* Xl4 = (float4*)Xl;
#pragma unroll
    for (int i = 0; i < 4; ++i) Xl4[t + 256 * i] = x4[t + 256 * i];

    __syncthreads();

    const int tx = t & 31;
    const int ty = t >> 5;
    float acc[4][4];
#pragma unroll
    for (int i = 0; i < 4; ++i)
#pragma unroll
        for (int j = 0; j < 4; ++j) acc[i][j] = 0.f;

    for (int k = 0; k < 128; ++k) {
        float4 w = *(const float4*)&Wl[k * 128 + tx * 4];
        float xv[4];
#pragma unroll
        for (int i = 0; i < 4; ++i) xv[i] = Xl[(ty * 4 + i) * 128 + k];
#pragma unroll
        for (int i = 0; i < 4; ++i) {
            acc[i][0] += xv[i] * w.x;
            acc[i][1] += xv[i] * w.y;
            acc[i][2] += xv[i] * w.z;
            acc[i][3] += xv[i] * w.w;
        }
    }

#pragma unroll
    for (int i = 0; i < 4; ++i) {
        long r = rbase + ty * 4 + i;
        ushort4 o;
        o.x = f2bf(acc[i][0]); o.y = f2bf(acc[i][1]);
        o.z = f2bf(acc[i][2]); o.w = f2bf(acc[i][3]);
        *(ushort4*)&h[r * OUT_CH + tx * 4] = o;
    }
}

// ---------------------------------------------------------------------------
// K2: per-block bucket histogram (LDS only) -> blkcnt[bucket][block]
// ---------------------------------------------------------------------------
__global__ __launch_bounds__(256) void bucket_hist(const int* __restrict__ erow,
                                                   unsigned* __restrict__ blkcnt,
                                                   int n) {
    __shared__ unsigned cnt[NB];
    const int t = threadIdx.x, p = blockIdx.x;
    for (int i = t; i < NB; i += 256) cnt[i] = 0u;
    __syncthreads();
    const int e0 = p * BLK_E;
#pragma unroll
    for (int j = 0; j < 8; ++j) {
        int e = e0 + j * 256 + t;
        if (e < n) atomicAdd(&cnt[(unsigned)erow[e] >> 8], 1u);
    }
    __syncthreads();
    for (int i = t; i < NB; i += 256) blkcnt[(size_t)i * NBLK_P + p] = cnt[i];
}

// ---------------------------------------------------------------------------
// K3: per-bucket exclusive scan over blocks (in place) + bucket totals
// ---------------------------------------------------------------------------
__global__ __launch_bounds__(256) void scan_col(unsigned* __restrict__ blkcnt,
                                                unsigned* __restrict__ btotal,
                                                int nblk) {
    __shared__ unsigned part[256];
    const int b = blockIdx.x, t = threadIdx.x;
    unsigned* col = blkcnt + (size_t)b * NBLK_P;
    unsigned v[4];
    unsigned sum = 0;
    const int p0 = t * 4;
#pragma unroll
    for (int j = 0; j < 4; ++j) {
        int p = p0 + j;
        v[j] = (p < nblk) ? col[p] : 0u;
        sum += v[j];
    }
    part[t] = sum;
    __syncthreads();
    for (int off = 1; off < 256; off <<= 1) {
        unsigned a = (t >= off) ? part[t - off] : 0u;
        __syncthreads();
        part[t] += a;
        __syncthreads();
    }
    unsigned excl = part[t] - sum;
#pragma unroll
    for (int j = 0; j < 4; ++j) {
        int p = p0 + j;
        if (p < nblk) { unsigned tv = v[j]; col[p] = excl; excl += tv; }
    }
    if (t == 255) btotal[b] = part[255];
}

// ---------------------------------------------------------------------------
// K4: scan 391 bucket totals -> bucket bases; seed tail sentinels
// ---------------------------------------------------------------------------
__global__ __launch_bounds__(512) void scan_buckets(const unsigned* __restrict__ btotal,
                                                    unsigned* __restrict__ bbase,
                                                    unsigned* __restrict__ row_start,
                                                    int n_edges) {
    __shared__ unsigned s[512];
    const int t = threadIdx.x;
    unsigned v = (t < NB) ? btotal[t] : 0u;
    s[t] = v;
    __syncthreads();
    for (int off = 1; off < 512; off <<= 1) {
        unsigned a = (t >= off) ? s[t - off] : 0u;
        __syncthreads();
        s[t] += a;
        __syncthreads();
    }
    if (t < NB) bbase[t] = s[t] - v;
    if (t == 0) {
        bbase[NB] = (unsigned)n_edges;
        row_start[N_NODES] = (unsigned)n_edges;
    }
}

// ---------------------------------------------------------------------------
// K5: scatter edges into buckets — NO global atomics (deterministic bases)
// record.x = (row&255)<<17 | col    record.y = bits(w)
// ---------------------------------------------------------------------------
__global__ __launch_bounds__(256) void bucket_scatter(const int* __restrict__ erow,
                                                      const int* __restrict__ ecol,
                                                      const float* __restrict__ ew,
                                                      const unsigned* __restrict__ blkbase,
                                                      const unsigned* __restrict__ bbase,
                                                      uint2* __restrict__ brec,
                                                      int n) {
    __shared__ unsigned cnt[NB];
    __shared__ unsigned basec[NB];
    const int t = threadIdx.x, p = blockIdx.x;
    for (int i = t; i < NB; i += 256) {
        cnt[i] = 0u;
        basec[i] = bbase[i] + blkbase[(size_t)i * NBLK_P + p];
    }
    __syncthreads();
    const int e0 = p * BLK_E;
#pragma unroll
    for (int j = 0; j < 8; ++j) {
        int e = e0 + j * 256 + t;
        if (e < n) {
            unsigned r = (unsigned)erow[e];
            unsigned c = (unsigned)ecol[e];
            float w = ew[e];
            unsigned bk = r >> 8;
            unsigned rank = atomicAdd(&cnt[bk], 1u);    // LDS only
            brec[basec[bk] + rank] =
                make_uint2(((r & 255u) << 17) | c, __float_as_uint(w));
        }
    }
}

// ---------------------------------------------------------------------------
// K6: per-bucket row sort via LDS hist+scan; emits row_start for free.
// One block per bucket; records staged in LDS (~32KB typical).
// ---------------------------------------------------------------------------
__global__ __launch_bounds__(256) void row_scatter(const uint2* __restrict__ brec,
                                                   const unsigned* __restrict__ bbase,
                                                   unsigned* __restrict__ row_start,
                                                   uint2* __restrict__ srec) {
    __shared__ unsigned hist[256], sc[256], cur[256];
    __shared__ uint2 recs[CAP_LDS];
    const int b = blockIdx.x, t = threadIdx.x;
    const unsigned s = bbase[b], e = bbase[b + 1];
    const unsigned m = e - s;
    hist[t] = 0u;
    __syncthreads();
    const bool fits = (m <= CAP_LDS);
    if (fits) {
        for (unsigned i = t; i < m; i += 256) {
            uint2 rc = brec[s + i];
            recs[i] = rc;
            atomicAdd(&hist[rc.x >> 17], 1u);
        }
    } else {
        for (unsigned i = t; i < m; i += 256)
            atomicAdd(&hist[brec[s + i].x >> 17], 1u);
    }
    __syncthreads();
    unsigned v = hist[t];
    sc[t] = v;
    __syncthreads();
    for (int off = 1; off < 256; off <<= 1) {
        unsigned a = (t >= off) ? sc[t - off] : 0u;
        __syncthreads();
        sc[t] += a;
        __syncthreads();
    }
    const unsigned gpos = s + sc[t] - v;                 // global row start
    const int grow = b * 256 + t;
    if (grow < N_NODES) row_start[grow] = gpos;
    cur[t] = gpos;
    __syncthreads();
    if (fits) {
        for (unsigned i = t; i < m; i += 256) {
            uint2 rc = recs[i];
            unsigned pos = atomicAdd(&cur[rc.x >> 17], 1u);   // LDS only
            srec[pos] = make_uint2(rc.x & 0x1FFFFu, rc.y);
        }
    } else {
        for (unsigned i = t; i < m; i += 256) {
            uint2 rc = brec[s + i];
            unsigned pos = atomicAdd(&cur[rc.x >> 17], 1u);
            srec[pos] = make_uint2(rc.x & 0x1FFFFu, rc.y);
        }
    }
}

// ---------------------------------------------------------------------------
// K7: out[r] = bias + sum w_e * h[col_e]   (register accumulation)
// 16 lanes/row (8 ch = 16B/lane); 4 row-chains/wave; 4x unroll.
// ---------------------------------------------------------------------------
__global__ __launch_bounds__(256) void aggregate(const unsigned short* __restrict__ h,
                                                 const uint2* __restrict__ srec,
                                                 const unsigned* __restrict__ row_start,
                                                 const float* __restrict__ bias,
                                                 float* __restrict__ out) {
    const int t = threadIdx.x, lane = t & 15;
    const int r = blockIdx.x * 16 + (t >> 4);
    if (r >= N_NODES) return;
    const unsigned s = row_start[r], e = row_start[r + 1];

    const float4* b4 = (const float4*)bias;
    float4 a0 = b4[lane * 2];
    float4 a1 = b4[lane * 2 + 1];

    const uint4* h16 = (const uint4*)h;

    unsigned i = s;
    for (; i + 4 <= e; i += 4) {
        uint2 r0 = srec[i];
        uint2 r1 = srec[i + 1];
        uint2 r2 = srec[i + 2];
        uint2 r3 = srec[i + 3];
        uint4 v0 = h16[(size_t)r0.x * 16 + lane];
        uint4 v1 = h16[(size_t)r1.x * 16 + lane];
        uint4 v2 = h16[(size_t)r2.x * 16 + lane];
        uint4 v3 = h16[(size_t)r3.x * 16 + lane];
        accum8(a0, a1, v0, __uint_as_float(r0.y));
        accum8(a0, a1, v1, __uint_as_float(r1.y));
        accum8(a0, a1, v2, __uint_as_float(r2.y));
        accum8(a0, a1, v3, __uint_as_float(r3.y));
    }
    for (; i < e; ++i) {
        uint2 rc = srec[i];
        uint4 vv = h16[(size_t)rc.x * 16 + lane];
        accum8(a0, a1, vv, __uint_as_float(rc.y));
    }

    float4* o = (float4*)(out + (size_t)r * OUT_CH + lane * 8);
    o[0] = a0;
    o[1] = a1;
}

// ---------------------------------------------------------------------------
// Fallback (atomic) path if ws_size too small
// ---------------------------------------------------------------------------
__global__ __launch_bounds__(256) void init_bias(float* __restrict__ out,
                                                 const float* __restrict__ bias) {
    int idx = blockIdx.x * 256 + threadIdx.x;
    float4 b = ((const float4*)bias)[idx & 31];
    ((float4*)out)[idx] = b;
}

__global__ __launch_bounds__(256) void spmm_scatter(const unsigned short* __restrict__ h,
                                                    const int* __restrict__ erow,
                                                    const int* __restrict__ ecol,
                                                    const float* __restrict__ ew,
                                                    float* __restrict__ out,
                                                    int n_edges) {
    const int t = threadIdx.x;
    const int lane = t & 31;
    const int e = blockIdx.x * 8 + (t >> 5);
    if (e >= n_edges) return;
    const int r = erow[e];
    const int c = ecol[e];
    const float w = ew[e];
    ushort4 hv = ((const ushort4*)(h + (size_t)c * OUT_CH))[lane];
    float* o = out + (size_t)r * OUT_CH + lane * 4;
    atomicAdd(o + 0, w * bf2f(hv.x));
    atomicAdd(o + 1, w * bf2f(hv.y));
    atomicAdd(o + 2, w * bf2f(hv.z));
    atomicAdd(o + 3, w * bf2f(hv.w));
}

extern "C" void kernel_launch(void* const* d_in, const int* in_sizes, int n_in,
                              void* d_out, int out_size, void* d_ws, size_t ws_size,
                              hipStream_t stream) {
    const float* x    = (const float*)d_in[0];
    const float* W    = (const float*)d_in[1];
    const float* bias = (const float*)d_in[2];
    const int*   erow = (const int*)d_in[3];
    const int*   ecol = (const int*)d_in[4];
    const float* ew   = (const float*)d_in[5];
    float* out = (float*)d_out;
    const int n_edges = in_sizes[3];

    char* ws = (char*)d_ws;
    unsigned short* h  = (unsigned short*)(ws + H_OFF);
    uint2*    brec     = (uint2*)(ws + BREC_OFF);
    uint2*    srec     = (uint2*)(ws + SREC_OFF);
    unsigned* blkcnt   = (unsigned*)(ws + BLK_OFF);
    unsigned* btotal   = (unsigned*)(ws + BTOT_OFF);
    unsigned* bbase    = (unsigned*)(ws + BBASE_OFF);
    unsigned* rowstart = (unsigned*)(ws + RS_OFF);

    gemm_xw<<<N_NODES / 32, 256, 0, stream>>>(x, W, h);

    const int nblk = (n_edges + BLK_E - 1) / BLK_E;
    if (ws_size >= WS_NEED && n_edges <= N_EDGES_MAX) {
        bucket_hist<<<nblk, 256, 0, stream>>>(erow, blkcnt, n_edges);
        scan_col<<<NB, 256, 0, stream>>>(blkcnt, btotal, nblk);
        scan_buckets<<<1, 512, 0, stream>>>(btotal, bbase, rowstart, n_edges);
        bucket_scatter<<<nblk, 256, 0, stream>>>(erow, ecol, ew, blkcnt, bbase,
                                                 brec, n_edges);
        row_scatter<<<NB, 256, 0, stream>>>(brec, bbase, rowstart, srec);
        aggregate<<<(N_NODES + 15) / 16, 256, 0, stream>>>(h, srec, rowstart,
                                                           bias, out);
    } else {
        init_bias<<<(N_NODES * 32) / 256, 256, 0, stream>>>(out, bias);
        spmm_scatter<<<(n_edges + 7) / 8, 256, 0, stream>>>(h, erow, ecol, ew,
                                                            out, n_edges);
    }
}